// Round 1
// baseline (1062.211 us; speedup 1.0000x reference)
//
#include <hip/hip_runtime.h>
#include <stdint.h>

// B=512, N=256, D=512.
// merged = ((softmax(msg A msg^T) col-sums) @ msg) @ Wv,  A = Wq Wk^T / sqrt(D)

typedef __attribute__((ext_vector_type(8))) short short8;
typedef __attribute__((ext_vector_type(4))) float f32x4;

#define MFMA16(a,b,c) __builtin_amdgcn_mfma_f32_16x16x32_bf16((a),(b),(c),0,0,0)

__device__ __forceinline__ uint16_t f2bf(float f){
  uint32_t x = __float_as_uint(f);
  uint32_t r = (x + 0x7FFFu + ((x >> 16) & 1u)) >> 16;  // RNE
  return (uint16_t)r;
}

// ---------------- kernel 1: A_swz = swizzle(bf16(norm * Wq @ Wk^T)) ----------------
// Fragment-major layout: element A[k][c] lives at
//   idx = ((ct*16 + ks)*64 + lane)*8 + j,  ct=c>>4, ks=k>>5, lane=((k>>3)&3)*16 + (c&15), j=k&7
// so a wave's B-fragment load for (ct,ks) is lane-contiguous 16B (1KB/instr coalesced).
__global__ __launch_bounds__(256) void prep_a(const float* __restrict__ wq,
                                              const float* __restrict__ wk,
                                              uint16_t* __restrict__ aswz){
  __shared__ float sQ[64][17];
  __shared__ float sK[64][17];
  const int tid = threadIdx.x;
  const int k0 = blockIdx.y * 64, c0 = blockIdx.x * 64;
  const int tx = tid & 15, ty = tid >> 4;
  const int lr = tid >> 2, lc = (tid & 3) * 4;
  float acc[4][4] = {{0.f}};

  for (int e0 = 0; e0 < 512; e0 += 16){
    __syncthreads();
    float4 q4 = *(const float4*)(wq + (size_t)(k0 + lr) * 512 + e0 + lc);
    float4 k4 = *(const float4*)(wk + (size_t)(c0 + lr) * 512 + e0 + lc);
    sQ[lr][lc+0] = q4.x; sQ[lr][lc+1] = q4.y; sQ[lr][lc+2] = q4.z; sQ[lr][lc+3] = q4.w;
    sK[lr][lc+0] = k4.x; sK[lr][lc+1] = k4.y; sK[lr][lc+2] = k4.z; sK[lr][lc+3] = k4.w;
    __syncthreads();
    #pragma unroll
    for (int e = 0; e < 16; e++){
      float qv[4], kv[4];
      #pragma unroll
      for (int i = 0; i < 4; i++) qv[i] = sQ[ty + 16*i][e];
      #pragma unroll
      for (int j = 0; j < 4; j++) kv[j] = sK[tx + 16*j][e];
      #pragma unroll
      for (int i = 0; i < 4; i++)
        #pragma unroll
        for (int j = 0; j < 4; j++) acc[i][j] += qv[i] * kv[j];
    }
  }
  const float norm = 0.04419417382415922f;  // 1/sqrt(512)
  #pragma unroll
  for (int i = 0; i < 4; i++){
    #pragma unroll
    for (int j = 0; j < 4; j++){
      int k = k0 + ty + 16*i, c = c0 + tx + 16*j;
      int ks = k >> 5, q = (k >> 3) & 3, jj = k & 7, ct = c >> 4;
      int lane = q*16 + (c & 15);
      aswz[((size_t)((ct*16 + ks)*64 + lane))*8 + jj] = f2bf(acc[i][j] * norm);
    }
  }
}

// stage 64 rows x 512 cols fp32 -> bf16 LDS (row stride 520 bf16 = +16B pad)
__device__ __forceinline__ void stage64(const float* __restrict__ src, uint16_t* dst, int tid){
  #pragma unroll 4
  for (int it = 0; it < 32; it++){
    int idx = it*256 + tid;
    int row = idx >> 7;          // 128 float4 per row
    int c4  = idx & 127;
    const float4 v = *(const float4*)(src + row*512 + c4*4);
    uint2 pk;
    pk.x = (uint32_t)f2bf(v.x) | ((uint32_t)f2bf(v.y) << 16);
    pk.y = (uint32_t)f2bf(v.z) | ((uint32_t)f2bf(v.w) << 16);
    *(uint2*)(dst + row*520 + c4*4) = pk;
  }
}

// ---------------- kernel 2: per-batch fused attention merge ----------------
__global__ __launch_bounds__(256,1) void fused_attn(const float* __restrict__ msg,
                                                    const uint16_t* __restrict__ aswz,
                                                    const float* __restrict__ wvm,
                                                    float* __restrict__ out)
{
  __shared__ uint16_t sT[64*520];      // T chunk, bf16  (66.6 KB)
  __shared__ uint16_t sStage[64*520];  // staged msg rows (66.6 KB); reused as float u[512] at end
  __shared__ float sW4[4][256];        // per-wave attention column-sum accumulators

  const int tid  = threadIdx.x;
  const int b    = blockIdx.x;
  const int lane = tid & 63;
  const int w    = tid >> 6;           // wave id 0..3 -> n-strip
  const int l15  = lane & 15;
  const int q    = lane >> 4;
  const float* mbp = msg + (size_t)b * (256*512);
  const short8* Ag = (const short8*)aswz;

  ((float*)sW4)[tid]       = 0.f;
  ((float*)sW4)[tid + 256] = 0.f;
  ((float*)sW4)[tid + 512] = 0.f;
  ((float*)sW4)[tid + 768] = 0.f;

  #pragma unroll 1
  for (int nc = 0; nc < 4; nc++){
    // ---- phase 0: stage this chunk's 64 n-rows (bf16)
    __syncthreads();
    stage64(mbp + nc*64*512, sStage, tid);
    __syncthreads();

    // ---- phase 1: T strip (16 rows/wave x 512) = msg_rows @ A
    short8 aF[16];
    {
      const uint16_t* abase = sStage + (w*16 + l15)*520 + q*8;
      #pragma unroll
      for (int ks = 0; ks < 16; ks++) aF[ks] = *(const short8*)(abase + ks*32);
    }
    uint16_t* trow = sT + (w*16 + q*4)*520 + l15;
    for (int ct = 0; ct < 32; ct += 2){
      f32x4 a0 = {0.f,0.f,0.f,0.f}, a1 = {0.f,0.f,0.f,0.f};
      #pragma unroll
      for (int ks = 0; ks < 16; ks++){
        short8 b0 = Ag[(ct*16      + ks)*64 + lane];
        short8 b1 = Ag[(ct*16 + 16 + ks)*64 + lane];
        a0 = MFMA16(aF[ks], b0, a0);
        a1 = MFMA16(aF[ks], b1, a1);
      }
      #pragma unroll
      for (int r = 0; r < 4; r++){
        trow[r*520 + ct*16]      = f2bf(a0[r]);   // C-layout: col=l15, row=q*4+r
        trow[r*520 + ct*16 + 16] = f2bf(a1[r]);
      }
    }

    // ---- phase 2: S strip (16 x 256) = T strip @ msg^T, m-panels of 64
    f32x4 accS[16];
    #pragma unroll
    for (int t = 0; t < 16; t++) accS[t] = (f32x4){0.f,0.f,0.f,0.f};
    short8 aT[16];
    {
      const uint16_t* tbase = sT + (w*16 + l15)*520 + q*8;   // same-wave RAW, in-order DS
      #pragma unroll
      for (int ks = 0; ks < 16; ks++) aT[ks] = *(const short8*)(tbase + ks*32);
    }
    #pragma unroll
    for (int mp = 0; mp < 4; mp++){
      __syncthreads();
      stage64(mbp + mp*64*512, sStage, tid);
      __syncthreads();
      const uint16_t* b0p = sStage + (     l15)*520 + q*8;
      const uint16_t* b1p = sStage + (16 + l15)*520 + q*8;
      const uint16_t* b2p = sStage + (32 + l15)*520 + q*8;
      const uint16_t* b3p = sStage + (48 + l15)*520 + q*8;
      #pragma unroll
      for (int ks = 0; ks < 16; ks++){
        short8 bb0 = *(const short8*)(b0p + ks*32);
        short8 bb1 = *(const short8*)(b1p + ks*32);
        short8 bb2 = *(const short8*)(b2p + ks*32);
        short8 bb3 = *(const short8*)(b3p + ks*32);
        accS[mp*4+0] = MFMA16(aT[ks], bb0, accS[mp*4+0]);
        accS[mp*4+1] = MFMA16(aT[ks], bb1, accS[mp*4+1]);
        accS[mp*4+2] = MFMA16(aT[ks], bb2, accS[mp*4+2]);
        accS[mp*4+3] = MFMA16(aT[ks], bb3, accS[mp*4+3]);
      }
    }

    // ---- phase 3: fp32 softmax per row (rows live in 16-lane groups) + col sums
    float mx[4], inv[4];
    #pragma unroll
    for (int r = 0; r < 4; r++){
      float m_ = accS[0][r];
      #pragma unroll
      for (int t = 1; t < 16; t++) m_ = fmaxf(m_, accS[t][r]);
      m_ = fmaxf(m_, __shfl_xor(m_, 1));
      m_ = fmaxf(m_, __shfl_xor(m_, 2));
      m_ = fmaxf(m_, __shfl_xor(m_, 4));
      m_ = fmaxf(m_, __shfl_xor(m_, 8));
      mx[r] = m_;
    }
    #pragma unroll
    for (int t = 0; t < 16; t++){
      #pragma unroll
      for (int r = 0; r < 4; r++) accS[t][r] = __expf(accS[t][r] - mx[r]);
    }
    #pragma unroll
    for (int r = 0; r < 4; r++){
      float s_ = 0.f;
      #pragma unroll
      for (int t = 0; t < 16; t++) s_ += accS[t][r];
      s_ += __shfl_xor(s_, 1);
      s_ += __shfl_xor(s_, 2);
      s_ += __shfl_xor(s_, 4);
      s_ += __shfl_xor(s_, 8);
      inv[r] = 1.f / s_;
    }
    #pragma unroll
    for (int t = 0; t < 16; t++){
      float wc = accS[t][0]*inv[0] + accS[t][1]*inv[1] + accS[t][2]*inv[2] + accS[t][3]*inv[3];
      wc += __shfl_xor(wc, 16);
      wc += __shfl_xor(wc, 32);
      if (lane < 16) sW4[w][t*16 + lane] += wc;   // col m = t*16+lane, distinct per lane, per-wave buffer
    }
  }

  // ---- combine w, u = w^T msg_b, merged = u @ Wv (all fp32)
  __syncthreads();
  {
    float wt = sW4[0][tid] + sW4[1][tid] + sW4[2][tid] + sW4[3][tid];
    sW4[0][tid] = wt;   // each index touched by exactly one thread
  }
  __syncthreads();
  float u0 = 0.f, u1 = 0.f;
  for (int m = 0; m < 256; m++){
    float ww = sW4[0][m];
    u0 += ww * mbp[m*512 + tid];
    u1 += ww * mbp[m*512 + tid + 256];
  }
  float* sU = (float*)sStage;
  sU[tid] = u0; sU[tid + 256] = u1;
  __syncthreads();
  float o0 = 0.f, o1 = 0.f;
  for (int d = 0; d < 512; d++){
    float ud = sU[d];
    o0 += ud * wvm[(size_t)d*512 + tid];
    o1 += ud * wvm[(size_t)d*512 + tid + 256];
  }
  out[(size_t)b*512 + tid]       = o0;
  out[(size_t)b*512 + tid + 256] = o1;
}

extern "C" void kernel_launch(void* const* d_in, const int* in_sizes, int n_in,
                              void* d_out, int out_size, void* d_ws, size_t ws_size,
                              hipStream_t stream) {
  const float* msg = (const float*)d_in[0];
  const float* wq  = (const float*)d_in[1];
  const float* wk  = (const float*)d_in[2];
  const float* wv  = (const float*)d_in[3];
  uint16_t* aswz = (uint16_t*)d_ws;            // 512 KB only
  prep_a<<<dim3(8,8), 256, 0, stream>>>(wq, wk, aswz);
  fused_attn<<<512, 256, 0, stream>>>(msg, aswz, wv, (float*)d_out);
}

// Round 2
// 971.836 us; speedup vs baseline: 1.0930x; 1.0930x over previous
//
#include <hip/hip_runtime.h>
#include <stdint.h>

// B=512, N=256, D=512.
// merged = ((softmax(msg A msg^T) col-sums) @ msg) @ Wv,  A = Wq Wk^T / sqrt(D)
// Pipeline: prep_a -> cast_msg -> gemm_T -> attn_w -> final_merge (ws >= ~258MiB)
// Fallback: round-1 fused kernel (ws >= 512KB only).

typedef __attribute__((ext_vector_type(8))) short short8;
typedef __attribute__((ext_vector_type(4))) float f32x4;

#define MFMA16(a,b,c) __builtin_amdgcn_mfma_f32_16x16x32_bf16((a),(b),(c),0,0,0)

__device__ __forceinline__ uint16_t f2bf(float f){
  uint32_t x = __float_as_uint(f);
  uint32_t r = (x + 0x7FFFu + ((x >> 16) & 1u)) >> 16;  // RNE
  return (uint16_t)r;
}
__device__ __forceinline__ float bf2f(uint16_t h){ return __uint_as_float(((uint32_t)h) << 16); }

// ---------------- kernel 1: A_swz = swizzle(bf16(norm * Wq @ Wk^T)) ----------------
// Fragment-major: A[k][c] at ((ct*16+ks)*64 + lane)*8 + j; ct=c>>4, ks=k>>5,
// lane=((k>>3)&3)*16 + (c&15), j=k&7  -> wave B-frag load is lane-contiguous 16B.
__global__ __launch_bounds__(256) void prep_a(const float* __restrict__ wq,
                                              const float* __restrict__ wk,
                                              uint16_t* __restrict__ aswz){
  __shared__ float sQ[64][17];
  __shared__ float sK[64][17];
  const int tid = threadIdx.x;
  const int k0 = blockIdx.y * 64, c0 = blockIdx.x * 64;
  const int tx = tid & 15, ty = tid >> 4;
  const int lr = tid >> 2, lc = (tid & 3) * 4;
  float acc[4][4] = {{0.f}};

  for (int e0 = 0; e0 < 512; e0 += 16){
    __syncthreads();
    float4 q4 = *(const float4*)(wq + (size_t)(k0 + lr) * 512 + e0 + lc);
    float4 k4 = *(const float4*)(wk + (size_t)(c0 + lr) * 512 + e0 + lc);
    sQ[lr][lc+0] = q4.x; sQ[lr][lc+1] = q4.y; sQ[lr][lc+2] = q4.z; sQ[lr][lc+3] = q4.w;
    sK[lr][lc+0] = k4.x; sK[lr][lc+1] = k4.y; sK[lr][lc+2] = k4.z; sK[lr][lc+3] = k4.w;
    __syncthreads();
    #pragma unroll
    for (int e = 0; e < 16; e++){
      float qv[4], kv[4];
      #pragma unroll
      for (int i = 0; i < 4; i++) qv[i] = sQ[ty + 16*i][e];
      #pragma unroll
      for (int j = 0; j < 4; j++) kv[j] = sK[tx + 16*j][e];
      #pragma unroll
      for (int i = 0; i < 4; i++)
        #pragma unroll
        for (int j = 0; j < 4; j++) acc[i][j] += qv[i] * kv[j];
    }
  }
  const float norm = 0.04419417382415922f;  // 1/sqrt(512)
  #pragma unroll
  for (int i = 0; i < 4; i++){
    #pragma unroll
    for (int j = 0; j < 4; j++){
      int k = k0 + ty + 16*i, c = c0 + tx + 16*j;
      int ks = k >> 5, q = (k >> 3) & 3, jj = k & 7, ct = c >> 4;
      int lane = q*16 + (c & 15);
      aswz[((size_t)((ct*16 + ks)*64 + lane))*8 + jj] = f2bf(acc[i][j] * norm);
    }
  }
}

// ---------------- kernel 2: msgbf = bf16(msg), row-major ----------------
__global__ __launch_bounds__(256) void cast_msg(const float* __restrict__ src,
                                                uint16_t* __restrict__ dst){
  size_t idx = ((size_t)blockIdx.x * 256 + threadIdx.x) * 8;  // 8 floats/thread
  float4 v0 = *(const float4*)(src + idx);
  float4 v1 = *(const float4*)(src + idx + 4);
  uint4 pk;
  pk.x = (uint32_t)f2bf(v0.x) | ((uint32_t)f2bf(v0.y) << 16);
  pk.y = (uint32_t)f2bf(v0.z) | ((uint32_t)f2bf(v0.w) << 16);
  pk.z = (uint32_t)f2bf(v1.x) | ((uint32_t)f2bf(v1.y) << 16);
  pk.w = (uint32_t)f2bf(v1.z) | ((uint32_t)f2bf(v1.w) << 16);
  *(uint4*)(dst + idx) = pk;
}

// ---------------- kernel 3: T = msgbf @ A  (rows = B*N = 131072, K=512) ----------------
// Per wave: 16 rows, A-frags (full K) register-resident; B-frags streamed from
// L2-hot A_swz. grid = (2048 row-blocks of 64, 2 e-halves of 256).
__global__ __launch_bounds__(256) void gemm_T(const uint16_t* __restrict__ msgbf,
                                              const uint16_t* __restrict__ aswz,
                                              uint16_t* __restrict__ T){
  __shared__ uint16_t sTr[4][16][264];
  const int tid = threadIdx.x, w = tid >> 6, lane = tid & 63;
  const int l15 = lane & 15, q = lane >> 4;
  const int r0 = blockIdx.x * 64 + w * 16;
  const int eh = blockIdx.y;

  const uint16_t* abase = msgbf + (size_t)(r0 + l15) * 512 + q * 8;
  short8 aF[16];
  #pragma unroll
  for (int ks = 0; ks < 16; ks++) aF[ks] = *(const short8*)(abase + ks*32);

  f32x4 acc[16];
  #pragma unroll
  for (int ct = 0; ct < 16; ct++) acc[ct] = (f32x4){0.f,0.f,0.f,0.f};

  const short8* Bg = (const short8*)aswz + (size_t)eh * 16*16*64 + lane;
  #pragma unroll 2
  for (int ct = 0; ct < 16; ct += 2){
    #pragma unroll
    for (int ks = 0; ks < 16; ks++){
      short8 b0 = Bg[(ct*16      + ks)*64];
      short8 b1 = Bg[((ct+1)*16  + ks)*64];
      acc[ct]   = MFMA16(aF[ks], b0, acc[ct]);
      acc[ct+1] = MFMA16(aF[ks], b1, acc[ct+1]);
    }
  }
  // epilogue: C-layout (col=l15, row=q*4+r) -> LDS -> coalesced row-major store
  #pragma unroll
  for (int ct = 0; ct < 16; ct++)
    #pragma unroll
    for (int r = 0; r < 4; r++)
      sTr[w][q*4 + r][ct*16 + l15] = f2bf(acc[ct][r]);
  // same-wave RAW through LDS: compiler inserts lgkmcnt wait
  #pragma unroll
  for (int r2 = 0; r2 < 16; r2++){
    *(uint2*)(T + (size_t)(r0 + r2) * 512 + eh*256 + lane*4) =
        *(const uint2*)&sTr[w][r2][lane*4];
  }
}

// ---------------- kernel 4: S = T_b @ msgbf_b^T, softmax rows, column sums ----------------
// grid = 1024 (b, n-half of 128 rows), 512 threads = 8 waves x 16 rows.
__global__ __launch_bounds__(512) void attn_w(const uint16_t* __restrict__ T,
                                              const uint16_t* __restrict__ msgbf,
                                              float* __restrict__ w4){
  __shared__ uint16_t sP[64*520];   // 66.6 KB m-panel
  __shared__ float sW[8][256];
  const int tid = threadIdx.x, w = tid >> 6, lane = tid & 63;
  const int l15 = lane & 15, q = lane >> 4;
  const int b = blockIdx.x >> 1, nh = blockIdx.x & 1;
  const int n0 = nh*128 + w*16;

  const uint16_t* abase = T + ((size_t)b*256 + n0 + l15) * 512 + q*8;
  short8 aT[16];
  #pragma unroll
  for (int ks = 0; ks < 16; ks++) aT[ks] = *(const short8*)(abase + ks*32);

  f32x4 acc[16];
  #pragma unroll
  for (int t = 0; t < 16; t++) acc[t] = (f32x4){0.f,0.f,0.f,0.f};

  for (int mp = 0; mp < 4; mp++){
    __syncthreads();
    #pragma unroll
    for (int it = 0; it < 8; it++){
      int idx = it*512 + tid;
      int row = idx >> 6, c = idx & 63;   // 64 uint4 per 512-short row
      *(uint4*)(sP + row*520 + c*8) =
          *(const uint4*)(msgbf + ((size_t)b*256 + mp*64 + row)*512 + c*8);
    }
    __syncthreads();
    #pragma unroll
    for (int ks = 0; ks < 16; ks++){
      const uint16_t* bp = sP + l15*520 + q*8 + ks*32;
      short8 b0 = *(const short8*)(bp);
      short8 b1 = *(const short8*)(bp + 16*520);
      short8 b2 = *(const short8*)(bp + 32*520);
      short8 b3 = *(const short8*)(bp + 48*520);
      acc[mp*4+0] = MFMA16(aT[ks], b0, acc[mp*4+0]);
      acc[mp*4+1] = MFMA16(aT[ks], b1, acc[mp*4+1]);
      acc[mp*4+2] = MFMA16(aT[ks], b2, acc[mp*4+2]);
      acc[mp*4+3] = MFMA16(aT[ks], b3, acc[mp*4+3]);
    }
  }

  // softmax per row (row n = n0+q*4+r, cols m = t*16 + l15), then column sums
  float mx[4], inv[4];
  #pragma unroll
  for (int r = 0; r < 4; r++){
    float m_ = acc[0][r];
    #pragma unroll
    for (int t = 1; t < 16; t++) m_ = fmaxf(m_, acc[t][r]);
    m_ = fmaxf(m_, __shfl_xor(m_, 1));
    m_ = fmaxf(m_, __shfl_xor(m_, 2));
    m_ = fmaxf(m_, __shfl_xor(m_, 4));
    m_ = fmaxf(m_, __shfl_xor(m_, 8));
    mx[r] = m_;
  }
  #pragma unroll
  for (int t = 0; t < 16; t++){
    #pragma unroll
    for (int r = 0; r < 4; r++) acc[t][r] = __expf(acc[t][r] - mx[r]);
  }
  #pragma unroll
  for (int r = 0; r < 4; r++){
    float s_ = 0.f;
    #pragma unroll
    for (int t = 0; t < 16; t++) s_ += acc[t][r];
    s_ += __shfl_xor(s_, 1);
    s_ += __shfl_xor(s_, 2);
    s_ += __shfl_xor(s_, 4);
    s_ += __shfl_xor(s_, 8);
    inv[r] = 1.f / s_;
  }
  #pragma unroll
  for (int t = 0; t < 16; t++){
    float wc = acc[t][0]*inv[0] + acc[t][1]*inv[1] + acc[t][2]*inv[2] + acc[t][3]*inv[3];
    wc += __shfl_xor(wc, 16);
    wc += __shfl_xor(wc, 32);
    if (lane < 16) sW[w][t*16 + lane] = wc;
  }
  __syncthreads();
  if (tid < 256){
    float s = 0.f;
    #pragma unroll
    for (int ww = 0; ww < 8; ww++) s += sW[ww][tid];
    w4[(size_t)b*512 + nh*256 + tid] = s;
  }
}

// ---------------- kernel 5: u = w^T msgbf_b ; out_b = u @ Wv ----------------
__global__ __launch_bounds__(256) void final_merge(const uint16_t* __restrict__ msgbf,
                                                   const float* __restrict__ w4,
                                                   const float* __restrict__ wvm,
                                                   float* __restrict__ out){
  __shared__ float sWm[256];
  __shared__ float sU[512];
  const int tid = threadIdx.x, b = blockIdx.x;
  sWm[tid] = w4[(size_t)b*512 + tid] + w4[(size_t)b*512 + 256 + tid];
  __syncthreads();
  const uint16_t* mb = msgbf + (size_t)b * 131072;
  const int e0 = tid * 2;
  float u0 = 0.f, u1 = 0.f;
  #pragma unroll 4
  for (int m = 0; m < 256; m++){
    float wm = sWm[m];
    uint32_t v = *(const uint32_t*)(mb + (size_t)m*512 + e0);
    u0 += wm * bf2f((uint16_t)(v & 0xFFFFu));
    u1 += wm * bf2f((uint16_t)(v >> 16));
  }
  sU[e0] = u0; sU[e0+1] = u1;
  __syncthreads();
  float o0 = 0.f, o1 = 0.f;
  #pragma unroll 4
  for (int d = 0; d < 512; d++){
    float ud = sU[d];
    float2 wv2 = *(const float2*)(wvm + (size_t)d*512 + e0);
    o0 += ud * wv2.x; o1 += ud * wv2.y;
  }
  out[(size_t)b*512 + e0]     = o0;
  out[(size_t)b*512 + e0 + 1] = o1;
}

// ================= fallback: round-1 fused per-batch kernel =================
__device__ __forceinline__ void stage64(const float* __restrict__ src, uint16_t* dst, int tid){
  #pragma unroll 4
  for (int it = 0; it < 32; it++){
    int idx = it*256 + tid;
    int row = idx >> 7;
    int c4  = idx & 127;
    const float4 v = *(const float4*)(src + row*512 + c4*4);
    uint2 pk;
    pk.x = (uint32_t)f2bf(v.x) | ((uint32_t)f2bf(v.y) << 16);
    pk.y = (uint32_t)f2bf(v.z) | ((uint32_t)f2bf(v.w) << 16);
    *(uint2*)(dst + row*520 + c4*4) = pk;
  }
}

__global__ __launch_bounds__(256,1) void fused_attn(const float* __restrict__ msg,
                                                    const uint16_t* __restrict__ aswz,
                                                    const float* __restrict__ wvm,
                                                    float* __restrict__ out)
{
  __shared__ uint16_t sT[64*520];
  __shared__ uint16_t sStage[64*520];
  __shared__ float sW4[4][256];

  const int tid  = threadIdx.x;
  const int b    = blockIdx.x;
  const int lane = tid & 63;
  const int w    = tid >> 6;
  const int l15  = lane & 15;
  const int q    = lane >> 4;
  const float* mbp = msg + (size_t)b * (256*512);
  const short8* Ag = (const short8*)aswz;

  ((float*)sW4)[tid]       = 0.f;
  ((float*)sW4)[tid + 256] = 0.f;
  ((float*)sW4)[tid + 512] = 0.f;
  ((float*)sW4)[tid + 768] = 0.f;

  #pragma unroll 1
  for (int nc = 0; nc < 4; nc++){
    __syncthreads();
    stage64(mbp + nc*64*512, sStage, tid);
    __syncthreads();

    short8 aF[16];
    {
      const uint16_t* abase = sStage + (w*16 + l15)*520 + q*8;
      #pragma unroll
      for (int ks = 0; ks < 16; ks++) aF[ks] = *(const short8*)(abase + ks*32);
    }
    uint16_t* trow = sT + (w*16 + q*4)*520 + l15;
    for (int ct = 0; ct < 32; ct += 2){
      f32x4 a0 = {0.f,0.f,0.f,0.f}, a1 = {0.f,0.f,0.f,0.f};
      #pragma unroll
      for (int ks = 0; ks < 16; ks++){
        short8 b0 = Ag[(ct*16      + ks)*64 + lane];
        short8 b1 = Ag[(ct*16 + 16 + ks)*64 + lane];
        a0 = MFMA16(aF[ks], b0, a0);
        a1 = MFMA16(aF[ks], b1, a1);
      }
      #pragma unroll
      for (int r = 0; r < 4; r++){
        trow[r*520 + ct*16]      = f2bf(a0[r]);
        trow[r*520 + ct*16 + 16] = f2bf(a1[r]);
      }
    }

    f32x4 accS[16];
    #pragma unroll
    for (int t = 0; t < 16; t++) accS[t] = (f32x4){0.f,0.f,0.f,0.f};
    short8 aT[16];
    {
      const uint16_t* tbase = sT + (w*16 + l15)*520 + q*8;
      #pragma unroll
      for (int ks = 0; ks < 16; ks++) aT[ks] = *(const short8*)(tbase + ks*32);
    }
    #pragma unroll
    for (int mp = 0; mp < 4; mp++){
      __syncthreads();
      stage64(mbp + mp*64*512, sStage, tid);
      __syncthreads();
      const uint16_t* b0p = sStage + (     l15)*520 + q*8;
      const uint16_t* b1p = sStage + (16 + l15)*520 + q*8;
      const uint16_t* b2p = sStage + (32 + l15)*520 + q*8;
      const uint16_t* b3p = sStage + (48 + l15)*520 + q*8;
      #pragma unroll
      for (int ks = 0; ks < 16; ks++){
        short8 bb0 = *(const short8*)(b0p + ks*32);
        short8 bb1 = *(const short8*)(b1p + ks*32);
        short8 bb2 = *(const short8*)(b2p + ks*32);
        short8 bb3 = *(const short8*)(b3p + ks*32);
        accS[mp*4+0] = MFMA16(aT[ks], bb0, accS[mp*4+0]);
        accS[mp*4+1] = MFMA16(aT[ks], bb1, accS[mp*4+1]);
        accS[mp*4+2] = MFMA16(aT[ks], bb2, accS[mp*4+2]);
        accS[mp*4+3] = MFMA16(aT[ks], bb3, accS[mp*4+3]);
      }
    }

    float mx[4], inv[4];
    #pragma unroll
    for (int r = 0; r < 4; r++){
      float m_ = accS[0][r];
      #pragma unroll
      for (int t = 1; t < 16; t++) m_ = fmaxf(m_, accS[t][r]);
      m_ = fmaxf(m_, __shfl_xor(m_, 1));
      m_ = fmaxf(m_, __shfl_xor(m_, 2));
      m_ = fmaxf(m_, __shfl_xor(m_, 4));
      m_ = fmaxf(m_, __shfl_xor(m_, 8));
      mx[r] = m_;
    }
    #pragma unroll
    for (int t = 0; t < 16; t++){
      #pragma unroll
      for (int r = 0; r < 4; r++) accS[t][r] = __expf(accS[t][r] - mx[r]);
    }
    #pragma unroll
    for (int r = 0; r < 4; r++){
      float s_ = 0.f;
      #pragma unroll
      for (int t = 0; t < 16; t++) s_ += accS[t][r];
      s_ += __shfl_xor(s_, 1);
      s_ += __shfl_xor(s_, 2);
      s_ += __shfl_xor(s_, 4);
      s_ += __shfl_xor(s_, 8);
      inv[r] = 1.f / s_;
    }
    #pragma unroll
    for (int t = 0; t < 16; t++){
      float wc = accS[t][0]*inv[0] + accS[t][1]*inv[1] + accS[t][2]*inv[2] + accS[t][3]*inv[3];
      wc += __shfl_xor(wc, 16);
      wc += __shfl_xor(wc, 32);
      if (lane < 16) sW4[w][t*16 + lane] += wc;
    }
  }

  __syncthreads();
  {
    float wt = sW4[0][tid] + sW4[1][tid] + sW4[2][tid] + sW4[3][tid];
    sW4[0][tid] = wt;
  }
  __syncthreads();
  float u0 = 0.f, u1 = 0.f;
  for (int m = 0; m < 256; m++){
    float ww = sW4[0][m];
    u0 += ww * mbp[m*512 + tid];
    u1 += ww * mbp[m*512 + tid + 256];
  }
  float* sU = (float*)sStage;
  sU[tid] = u0; sU[tid + 256] = u1;
  __syncthreads();
  float o0 = 0.f, o1 = 0.f;
  for (int d = 0; d < 512; d++){
    float ud = sU[d];
    o0 += ud * wvm[(size_t)d*512 + tid];
    o1 += ud * wvm[(size_t)d*512 + tid + 256];
  }
  out[(size_t)b*512 + tid]       = o0;
  out[(size_t)b*512 + tid + 256] = o1;
}

extern "C" void kernel_launch(void* const* d_in, const int* in_sizes, int n_in,
                              void* d_out, int out_size, void* d_ws, size_t ws_size,
                              hipStream_t stream) {
  const float* msg = (const float*)d_in[0];
  const float* wq  = (const float*)d_in[1];
  const float* wk  = (const float*)d_in[2];
  const float* wv  = (const float*)d_in[3];

  const size_t SZ_A   = 524288;                 // A_swz bf16 512x512
  const size_t SZ_MSG = 134217728;              // msgbf
  const size_t SZ_T   = 134217728;              // T bf16
  const size_t SZ_W   = 1048576;                // w slots fp32 512x2x256
  const size_t REQ = SZ_A + SZ_MSG + SZ_T + SZ_W;

  uint16_t* aswz = (uint16_t*)d_ws;
  prep_a<<<dim3(8,8), 256, 0, stream>>>(wq, wk, aswz);

  if (ws_size >= REQ){
    uint16_t* msgbf = (uint16_t*)((char*)d_ws + SZ_A);
    uint16_t* T     = (uint16_t*)((char*)d_ws + SZ_A + SZ_MSG);
    float*    w4    = (float*)   ((char*)d_ws + SZ_A + SZ_MSG + SZ_T);
    cast_msg  <<<32768, 256, 0, stream>>>(msg, msgbf);
    gemm_T    <<<dim3(2048,2), 256, 0, stream>>>(msgbf, aswz, T);
    attn_w    <<<1024, 512, 0, stream>>>(T, msgbf, w4);
    final_merge<<<512, 256, 0, stream>>>(msgbf, w4, wv, (float*)d_out);
  } else {
    fused_attn<<<512, 256, 0, stream>>>(msg, aswz, wv, (float*)d_out);
  }
}

// Round 3
// 703.293 us; speedup vs baseline: 1.5103x; 1.3818x over previous
//
#include <hip/hip_runtime.h>
#include <stdint.h>

// B=512, N=256, D=512.
// merged = ((softmax(msg A msg^T) col-sums) @ msg) @ Wv,  A = Wq Wk^T / sqrt(D)
// Pipeline: prep_a -> gemm_T2 -> attn_w -> final_merge  (ws >= ~136MiB)
// Fallback: round-1 fused kernel (ws >= 512KB only).

typedef __attribute__((ext_vector_type(8))) short short8;
typedef __attribute__((ext_vector_type(4))) float f32x4;

#define MFMA16(a,b,c) __builtin_amdgcn_mfma_f32_16x16x32_bf16((a),(b),(c),0,0,0)

__device__ __forceinline__ uint16_t f2bf(float f){
  uint32_t x = __float_as_uint(f);
  uint32_t r = (x + 0x7FFFu + ((x >> 16) & 1u)) >> 16;  // RNE
  return (uint16_t)r;
}

// ---------------- kernel 1: A_swz = swizzle(bf16(norm * Wq @ Wk^T)) ----------------
// Fragment-major: A[k][c] at ((ct*16+ks)*64 + lane)*8 + j; ct=c>>4, ks=k>>5,
// lane=((k>>3)&3)*16 + (c&15), j=k&7  -> chunk for a ct is 16KB contiguous.
__global__ __launch_bounds__(256) void prep_a(const float* __restrict__ wq,
                                              const float* __restrict__ wk,
                                              uint16_t* __restrict__ aswz){
  __shared__ float sQ[64][17];
  __shared__ float sK[64][17];
  const int tid = threadIdx.x;
  const int k0 = blockIdx.y * 64, c0 = blockIdx.x * 64;
  const int tx = tid & 15, ty = tid >> 4;
  const int lr = tid >> 2, lc = (tid & 3) * 4;
  float acc[4][4] = {{0.f}};

  for (int e0 = 0; e0 < 512; e0 += 16){
    __syncthreads();
    float4 q4 = *(const float4*)(wq + (size_t)(k0 + lr) * 512 + e0 + lc);
    float4 k4 = *(const float4*)(wk + (size_t)(c0 + lr) * 512 + e0 + lc);
    sQ[lr][lc+0] = q4.x; sQ[lr][lc+1] = q4.y; sQ[lr][lc+2] = q4.z; sQ[lr][lc+3] = q4.w;
    sK[lr][lc+0] = k4.x; sK[lr][lc+1] = k4.y; sK[lr][lc+2] = k4.z; sK[lr][lc+3] = k4.w;
    __syncthreads();
    #pragma unroll
    for (int e = 0; e < 16; e++){
      float qv[4], kv[4];
      #pragma unroll
      for (int i = 0; i < 4; i++) qv[i] = sQ[ty + 16*i][e];
      #pragma unroll
      for (int j = 0; j < 4; j++) kv[j] = sK[tx + 16*j][e];
      #pragma unroll
      for (int i = 0; i < 4; i++)
        #pragma unroll
        for (int j = 0; j < 4; j++) acc[i][j] += qv[i] * kv[j];
    }
  }
  const float norm = 0.04419417382415922f;  // 1/sqrt(512)
  #pragma unroll
  for (int i = 0; i < 4; i++){
    #pragma unroll
    for (int j = 0; j < 4; j++){
      int k = k0 + ty + 16*i, c = c0 + tx + 16*j;
      int ks = k >> 5, q = (k >> 3) & 3, jj = k & 7, ct = c >> 4;
      int lane = q*16 + (c & 15);
      aswz[((size_t)((ct*16 + ks)*64 + lane))*8 + jj] = f2bf(acc[i][j] * norm);
    }
  }
}

// ---------------- kernel 2: T = bf16(msg) @ A  (rows = B*N = 131072, K=512) ----------------
// Block: 4 waves x 32 rows = 128 rows, all 512 cols. A-frags register-resident
// (fp32 msg -> bf16 in-register). B (A_swz) staged per 32KB chunk (2 col-tiles
// x full K) into LDS, shared by all 4 waves. Acc live range = 1 chunk.
__global__ __launch_bounds__(256,2) void gemm_T2(const float* __restrict__ msg,
                                                 const uint16_t* __restrict__ aswz,
                                                 uint16_t* __restrict__ T){
  __shared__ __align__(16) uint16_t sB[16384];      // 32 KB chunk
  __shared__ __align__(16) uint16_t sE[4][32][40];  // per-wave epilogue transpose (10 KB)
  const int tid = threadIdx.x, w = tid >> 6, lane = tid & 63;
  const int l15 = lane & 15, q = lane >> 4;
  const int r0 = blockIdx.x * 128 + w * 32;

  // A-fragments for 32 rows, full K=512: aLo rows r0+l15, aHi rows r0+16+l15
  short8 aLo[16], aHi[16];
  {
    const float* base0 = msg + (size_t)(r0 + l15) * 512 + q * 8;
    const float* base1 = msg + (size_t)(r0 + 16 + l15) * 512 + q * 8;
    #pragma unroll
    for (int ks = 0; ks < 16; ks++){
      float4 x0 = *(const float4*)(base0 + ks*32);
      float4 x1 = *(const float4*)(base0 + ks*32 + 4);
      float4 y0 = *(const float4*)(base1 + ks*32);
      float4 y1 = *(const float4*)(base1 + ks*32 + 4);
      short8 a, b;
      a[0]=(short)f2bf(x0.x); a[1]=(short)f2bf(x0.y); a[2]=(short)f2bf(x0.z); a[3]=(short)f2bf(x0.w);
      a[4]=(short)f2bf(x1.x); a[5]=(short)f2bf(x1.y); a[6]=(short)f2bf(x1.z); a[7]=(short)f2bf(x1.w);
      b[0]=(short)f2bf(y0.x); b[1]=(short)f2bf(y0.y); b[2]=(short)f2bf(y0.z); b[3]=(short)f2bf(y0.w);
      b[4]=(short)f2bf(y1.x); b[5]=(short)f2bf(y1.y); b[6]=(short)f2bf(y1.z); b[7]=(short)f2bf(y1.w);
      aLo[ks] = a; aHi[ks] = b;
    }
  }

  #pragma unroll 1
  for (int cg = 0; cg < 16; cg++){
    __syncthreads();                         // all waves done reading previous sB
    {                                        // stage 32 KB chunk, coalesced uint4
      const uint4* gsrc = (const uint4*)(aswz + (size_t)cg * 16384);
      uint4* ldst = (uint4*)sB;
      #pragma unroll
      for (int p = 0; p < 8; p++)
        ldst[p*256 + tid] = gsrc[p*256 + tid];
    }
    __syncthreads();

    f32x4 a0 = {0.f,0.f,0.f,0.f}, a1 = {0.f,0.f,0.f,0.f};
    f32x4 a2 = {0.f,0.f,0.f,0.f}, a3 = {0.f,0.f,0.f,0.f};
    const uint16_t* b0p = sB + lane*8;           // ct-tile 0 frags
    const uint16_t* b1p = sB + 8192 + lane*8;    // ct-tile 1 frags
    #pragma unroll
    for (int ks = 0; ks < 16; ks++){
      short8 b0 = *(const short8*)(b0p + ks*512);
      short8 b1 = *(const short8*)(b1p + ks*512);
      a0 = MFMA16(aLo[ks], b0, a0);
      a1 = MFMA16(aLo[ks], b1, a1);
      a2 = MFMA16(aHi[ks], b0, a2);
      a3 = MFMA16(aHi[ks], b1, a3);
    }

    // epilogue for this chunk: C-layout (col=l15, row=q*4+r) -> sE -> coalesced store
    #pragma unroll
    for (int r = 0; r < 4; r++){
      sE[w][q*4 + r][l15]           = f2bf(a0[r]);
      sE[w][q*4 + r][16 + l15]      = f2bf(a1[r]);
      sE[w][16 + q*4 + r][l15]      = f2bf(a2[r]);
      sE[w][16 + q*4 + r][16 + l15] = f2bf(a3[r]);
    }
    // same-wave RAW through LDS (compiler inserts lgkmcnt wait)
    #pragma unroll
    for (int pass = 0; pass < 2; pass++){
      int r2 = pass*16 + (lane >> 2);
      uint4 vv = *(const uint4*)&sE[w][r2][(lane & 3) * 8];
      *(uint4*)(T + (size_t)(r0 + r2) * 512 + cg*32 + (lane & 3) * 8) = vv;
    }
  }
}

// ---------------- kernel 3: S = T_b @ bf16(msg_b)^T, softmax rows, column sums ----------------
// grid = 1024 (b, n-half of 128 rows), 512 threads = 8 waves x 16 rows.
__global__ __launch_bounds__(512) void attn_w(const uint16_t* __restrict__ T,
                                              const float* __restrict__ msg,
                                              float* __restrict__ w4){
  __shared__ uint16_t sP[64*520];   // 66.6 KB m-panel (bf16)
  __shared__ float sW[8][256];
  const int tid = threadIdx.x, w = tid >> 6, lane = tid & 63;
  const int l15 = lane & 15, q = lane >> 4;
  const int b = blockIdx.x >> 1, nh = blockIdx.x & 1;
  const int n0 = nh*128 + w*16;

  const uint16_t* abase = T + ((size_t)b*256 + n0 + l15) * 512 + q*8;
  short8 aT[16];
  #pragma unroll
  for (int ks = 0; ks < 16; ks++) aT[ks] = *(const short8*)(abase + ks*32);

  f32x4 acc[16];
  #pragma unroll
  for (int t = 0; t < 16; t++) acc[t] = (f32x4){0.f,0.f,0.f,0.f};

  for (int mp = 0; mp < 4; mp++){
    __syncthreads();
    // stage 64 msg rows fp32 -> bf16, 512 threads
    #pragma unroll
    for (int it = 0; it < 16; it++){
      int idx = it*512 + tid;
      int row = idx >> 7, c4 = idx & 127;
      const float4 v = *(const float4*)(msg + ((size_t)b*256 + mp*64 + row)*512 + c4*4);
      uint2 pk;
      pk.x = (uint32_t)f2bf(v.x) | ((uint32_t)f2bf(v.y) << 16);
      pk.y = (uint32_t)f2bf(v.z) | ((uint32_t)f2bf(v.w) << 16);
      *(uint2*)(sP + row*520 + c4*4) = pk;
    }
    __syncthreads();
    #pragma unroll
    for (int ks = 0; ks < 16; ks++){
      const uint16_t* bp = sP + l15*520 + q*8 + ks*32;
      short8 b0 = *(const short8*)(bp);
      short8 b1 = *(const short8*)(bp + 16*520);
      short8 b2 = *(const short8*)(bp + 32*520);
      short8 b3 = *(const short8*)(bp + 48*520);
      acc[mp*4+0] = MFMA16(aT[ks], b0, acc[mp*4+0]);
      acc[mp*4+1] = MFMA16(aT[ks], b1, acc[mp*4+1]);
      acc[mp*4+2] = MFMA16(aT[ks], b2, acc[mp*4+2]);
      acc[mp*4+3] = MFMA16(aT[ks], b3, acc[mp*4+3]);
    }
  }

  // softmax per row (row n = n0+q*4+r, cols m = t*16 + l15), then column sums
  float mx[4], inv[4];
  #pragma unroll
  for (int r = 0; r < 4; r++){
    float m_ = acc[0][r];
    #pragma unroll
    for (int t = 1; t < 16; t++) m_ = fmaxf(m_, acc[t][r]);
    m_ = fmaxf(m_, __shfl_xor(m_, 1));
    m_ = fmaxf(m_, __shfl_xor(m_, 2));
    m_ = fmaxf(m_, __shfl_xor(m_, 4));
    m_ = fmaxf(m_, __shfl_xor(m_, 8));
    mx[r] = m_;
  }
  #pragma unroll
  for (int t = 0; t < 16; t++){
    #pragma unroll
    for (int r = 0; r < 4; r++) acc[t][r] = __expf(acc[t][r] - mx[r]);
  }
  #pragma unroll
  for (int r = 0; r < 4; r++){
    float s_ = 0.f;
    #pragma unroll
    for (int t = 0; t < 16; t++) s_ += acc[t][r];
    s_ += __shfl_xor(s_, 1);
    s_ += __shfl_xor(s_, 2);
    s_ += __shfl_xor(s_, 4);
    s_ += __shfl_xor(s_, 8);
    inv[r] = 1.f / s_;
  }
  #pragma unroll
  for (int t = 0; t < 16; t++){
    float wc = acc[t][0]*inv[0] + acc[t][1]*inv[1] + acc[t][2]*inv[2] + acc[t][3]*inv[3];
    wc += __shfl_xor(wc, 16);
    wc += __shfl_xor(wc, 32);
    if (lane < 16) sW[w][t*16 + lane] = wc;
  }
  __syncthreads();
  if (tid < 256){
    float s = 0.f;
    #pragma unroll
    for (int ww = 0; ww < 8; ww++) s += sW[ww][tid];
    w4[(size_t)b*512 + nh*256 + tid] = s;
  }
}

// ---------------- kernel 4: u = w^T msg_b ; out_b = u @ Wv (fp32) ----------------
__global__ __launch_bounds__(256) void final_merge(const float* __restrict__ msg,
                                                   const float* __restrict__ w4,
                                                   const float* __restrict__ wvm,
                                                   float* __restrict__ out){
  __shared__ float sWm[256];
  __shared__ float sU[512];
  const int tid = threadIdx.x, b = blockIdx.x;
  sWm[tid] = w4[(size_t)b*512 + tid] + w4[(size_t)b*512 + 256 + tid];
  __syncthreads();
  const float* mb = msg + (size_t)b * 131072;
  const int e0 = tid * 2;
  float u0 = 0.f, u1 = 0.f;
  #pragma unroll 4
  for (int m = 0; m < 256; m++){
    float wm = sWm[m];
    float2 m2 = *(const float2*)(mb + (size_t)m*512 + e0);
    u0 += wm * m2.x;
    u1 += wm * m2.y;
  }
  sU[e0] = u0; sU[e0+1] = u1;
  __syncthreads();
  float o0 = 0.f, o1 = 0.f;
  #pragma unroll 4
  for (int d = 0; d < 512; d++){
    float ud = sU[d];
    float2 wv2 = *(const float2*)(wvm + (size_t)d*512 + e0);
    o0 += ud * wv2.x; o1 += ud * wv2.y;
  }
  out[(size_t)b*512 + e0]     = o0;
  out[(size_t)b*512 + e0 + 1] = o1;
}

// ================= fallback: round-1 fused per-batch kernel =================
__device__ __forceinline__ void stage64(const float* __restrict__ src, uint16_t* dst, int tid){
  #pragma unroll 4
  for (int it = 0; it < 32; it++){
    int idx = it*256 + tid;
    int row = idx >> 7;
    int c4  = idx & 127;
    const float4 v = *(const float4*)(src + row*512 + c4*4);
    uint2 pk;
    pk.x = (uint32_t)f2bf(v.x) | ((uint32_t)f2bf(v.y) << 16);
    pk.y = (uint32_t)f2bf(v.z) | ((uint32_t)f2bf(v.w) << 16);
    *(uint2*)(dst + row*520 + c4*4) = pk;
  }
}

__global__ __launch_bounds__(256,1) void fused_attn(const float* __restrict__ msg,
                                                    const uint16_t* __restrict__ aswz,
                                                    const float* __restrict__ wvm,
                                                    float* __restrict__ out)
{
  __shared__ uint16_t sT[64*520];
  __shared__ uint16_t sStage[64*520];
  __shared__ float sW4[4][256];

  const int tid  = threadIdx.x;
  const int b    = blockIdx.x;
  const int lane = tid & 63;
  const int w    = tid >> 6;
  const int l15  = lane & 15;
  const int q    = lane >> 4;
  const float* mbp = msg + (size_t)b * (256*512);
  const short8* Ag = (const short8*)aswz;

  ((float*)sW4)[tid]       = 0.f;
  ((float*)sW4)[tid + 256] = 0.f;
  ((float*)sW4)[tid + 512] = 0.f;
  ((float*)sW4)[tid + 768] = 0.f;

  #pragma unroll 1
  for (int nc = 0; nc < 4; nc++){
    __syncthreads();
    stage64(mbp + nc*64*512, sStage, tid);
    __syncthreads();

    short8 aF[16];
    {
      const uint16_t* abase = sStage + (w*16 + l15)*520 + q*8;
      #pragma unroll
      for (int ks = 0; ks < 16; ks++) aF[ks] = *(const short8*)(abase + ks*32);
    }
    uint16_t* trow = sT + (w*16 + q*4)*520 + l15;
    for (int ct = 0; ct < 32; ct += 2){
      f32x4 a0 = {0.f,0.f,0.f,0.f}, a1 = {0.f,0.f,0.f,0.f};
      #pragma unroll
      for (int ks = 0; ks < 16; ks++){
        short8 b0 = Ag[(ct*16      + ks)*64 + lane];
        short8 b1 = Ag[(ct*16 + 16 + ks)*64 + lane];
        a0 = MFMA16(aF[ks], b0, a0);
        a1 = MFMA16(aF[ks], b1, a1);
      }
      #pragma unroll
      for (int r = 0; r < 4; r++){
        trow[r*520 + ct*16]      = f2bf(a0[r]);
        trow[r*520 + ct*16 + 16] = f2bf(a1[r]);
      }
    }

    f32x4 accS[16];
    #pragma unroll
    for (int t = 0; t < 16; t++) accS[t] = (f32x4){0.f,0.f,0.f,0.f};
    short8 aT[16];
    {
      const uint16_t* tbase = sT + (w*16 + l15)*520 + q*8;
      #pragma unroll
      for (int ks = 0; ks < 16; ks++) aT[ks] = *(const short8*)(tbase + ks*32);
    }
    #pragma unroll
    for (int mp = 0; mp < 4; mp++){
      __syncthreads();
      stage64(mbp + mp*64*512, sStage, tid);
      __syncthreads();
      const uint16_t* b0p = sStage + (     l15)*520 + q*8;
      const uint16_t* b1p = sStage + (16 + l15)*520 + q*8;
      const uint16_t* b2p = sStage + (32 + l15)*520 + q*8;
      const uint16_t* b3p = sStage + (48 + l15)*520 + q*8;
      #pragma unroll
      for (int ks = 0; ks < 16; ks++){
        short8 bb0 = *(const short8*)(b0p + ks*32);
        short8 bb1 = *(const short8*)(b1p + ks*32);
        short8 bb2 = *(const short8*)(b2p + ks*32);
        short8 bb3 = *(const short8*)(b3p + ks*32);
        accS[mp*4+0] = MFMA16(aT[ks], bb0, accS[mp*4+0]);
        accS[mp*4+1] = MFMA16(aT[ks], bb1, accS[mp*4+1]);
        accS[mp*4+2] = MFMA16(aT[ks], bb2, accS[mp*4+2]);
        accS[mp*4+3] = MFMA16(aT[ks], bb3, accS[mp*4+3]);
      }
    }

    float mx[4], inv[4];
    #pragma unroll
    for (int r = 0; r < 4; r++){
      float m_ = accS[0][r];
      #pragma unroll
      for (int t = 1; t < 16; t++) m_ = fmaxf(m_, accS[t][r]);
      m_ = fmaxf(m_, __shfl_xor(m_, 1));
      m_ = fmaxf(m_, __shfl_xor(m_, 2));
      m_ = fmaxf(m_, __shfl_xor(m_, 4));
      m_ = fmaxf(m_, __shfl_xor(m_, 8));
      mx[r] = m_;
    }
    #pragma unroll
    for (int t = 0; t < 16; t++){
      #pragma unroll
      for (int r = 0; r < 4; r++) accS[t][r] = __expf(accS[t][r] - mx[r]);
    }
    #pragma unroll
    for (int r = 0; r < 4; r++){
      float s_ = 0.f;
      #pragma unroll
      for (int t = 0; t < 16; t++) s_ += accS[t][r];
      s_ += __shfl_xor(s_, 1);
      s_ += __shfl_xor(s_, 2);
      s_ += __shfl_xor(s_, 4);
      s_ += __shfl_xor(s_, 8);
      inv[r] = 1.f / s_;
    }
    #pragma unroll
    for (int t = 0; t < 16; t++){
      float wc = accS[t][0]*inv[0] + accS[t][1]*inv[1] + accS[t][2]*inv[2] + accS[t][3]*inv[3];
      wc += __shfl_xor(wc, 16);
      wc += __shfl_xor(wc, 32);
      if (lane < 16) sW4[w][t*16 + lane] += wc;
    }
  }

  __syncthreads();
  {
    float wt = sW4[0][tid] + sW4[1][tid] + sW4[2][tid] + sW4[3][tid];
    sW4[0][tid] = wt;
  }
  __syncthreads();
  float u0 = 0.f, u1 = 0.f;
  for (int m = 0; m < 256; m++){
    float ww = sW4[0][m];
    u0 += ww * mbp[m*512 + tid];
    u1 += ww * mbp[m*512 + tid + 256];
  }
  float* sU = (float*)sStage;
  sU[tid] = u0; sU[tid + 256] = u1;
  __syncthreads();
  float o0 = 0.f, o1 = 0.f;
  for (int d = 0; d < 512; d++){
    float ud = sU[d];
    o0 += ud * wvm[(size_t)d*512 + tid];
    o1 += ud * wvm[(size_t)d*512 + tid + 256];
  }
  out[(size_t)b*512 + tid]       = o0;
  out[(size_t)b*512 + tid + 256] = o1;
}

extern "C" void kernel_launch(void* const* d_in, const int* in_sizes, int n_in,
                              void* d_out, int out_size, void* d_ws, size_t ws_size,
                              hipStream_t stream) {
  const float* msg = (const float*)d_in[0];
  const float* wq  = (const float*)d_in[1];
  const float* wk  = (const float*)d_in[2];
  const float* wv  = (const float*)d_in[3];

  const size_t SZ_A = 524288;            // A_swz bf16 512x512
  const size_t SZ_T = 134217728;         // T bf16
  const size_t SZ_W = 1048576;           // w slots fp32
  const size_t REQ  = SZ_A + SZ_T + SZ_W;

  uint16_t* aswz = (uint16_t*)d_ws;
  prep_a<<<dim3(8,8), 256, 0, stream>>>(wq, wk, aswz);

  if (ws_size >= REQ){
    uint16_t* T  = (uint16_t*)((char*)d_ws + SZ_A);
    float*    w4 = (float*)   ((char*)d_ws + SZ_A + SZ_T);
    gemm_T2    <<<1024, 256, 0, stream>>>(msg, aswz, T);
    attn_w     <<<1024, 512, 0, stream>>>(T, msg, w4);
    final_merge<<<512, 256, 0, stream>>>(msg, w4, wv, (float*)d_out);
  } else {
    fused_attn<<<512, 256, 0, stream>>>(msg, aswz, wv, (float*)d_out);
  }
}